// Round 7
// baseline (447.166 us; speedup 1.0000x reference)
//
#include <hip/hip_runtime.h>

// TinyMLP (2 -> 32 -> 32 -> 1, sigmoid) analytic input-gradient, fused, MFMA-based.
// R6 (resubmit after infra failure): R5's 32-wide-batch 32x32x16 dataflow, restored to
// 8 waves/SIMD (R5 ran at 6 — unfounded VGPR fear, actual VGPR=40) + h1d carried in
// registers from layer 1 (drops the bf16 unpack+pk_fma recompute in the dz1 loop).
// TRANSPOSED dataflow: batch on the 32-wide column dim (lane&31) throughout;
// weights are wave-invariant A-operands; q5 = lane>>5 selects the h/k half.
//   MFMA z1  (x1): -log2e*Z1^T = A_z1 @ Y^T    (y hi/lo bf16 split, b1 in K-slots 6,7)
//   MFMA z2  (x2): -log2e*Z2^T = W2s @ H1^T    (K=32 chained; acc init = -log2e*b2)
//   MFMA dh1 (x2): dH1^T = (W2*W3) @ dZ2^T     (W3 folded into weights at init)
//   MFMA dy  (x2): dY^T  = W1 @ dZ1^T          (g1,g2 = regs 0,1 of lanes 0-31)
// Evidence through R5: VALUBusy 52% = 6 waves x (1082cy demand / 12.5Kcy wall) ->
// waves 91% stalled, pipe idle-slotted -> TLP-starved. NO cross-iteration register
// prefetch (R4: spill catastrophe, FETCH/WRITE x4-x7).
//
// Layouts (32x32x16 bf16; C verified m74/m101, A/B by analogy with verified 16x16x32):
//   A-frag: lane holds A[row=lane&31][k=(lane>>5)*8+j]
//   B-frag: lane holds B[k=(lane>>5)*8+j][n=lane&31]
//   C/D:    lane holds D[row=(reg&3)+8*(reg>>2)+4*(lane>>5)][col=lane&31]
//
// LDS pivot (per wave, two 1024-short regions R0/R1): value (batch b, k) at short
// index (k>>3)*256 + b*8 + (k&7). Writer lane (q5,b): reg pair (4t+e) has k =
// 8t+4q5+e -> one int2 at t*256 + b*8 + 4q5 per t (4x ds_write_b64). Reader lane
// (q5,n): 8 shorts at blk*256 + n*8 (ds_read_b128).

#define H 32
#define NLOG2E (-1.4426950408889634f)

typedef __attribute__((ext_vector_type(8))) short bf16x8;
typedef __attribute__((ext_vector_type(16))) float f32x16;
typedef __attribute__((ext_vector_type(4))) float f32x4;
typedef __attribute__((ext_vector_type(2))) float f32x2;
typedef __attribute__((ext_vector_type(2))) __bf16 bfx2;

#define MFMA32 __builtin_amdgcn_mfma_f32_32x32x16_bf16

__device__ __forceinline__ int cvt_pk_bf16(float a, float b) {
    f32x2 f; f[0] = a; f[1] = b;
    bfx2 r = __builtin_convertvector(f, bfx2);   // v_cvt_pk_bf16_f32 (RNE)
    return __builtin_bit_cast(int, r);
}
__device__ __forceinline__ float pklo(int p) {               // low bf16 of packed pair
    unsigned u = (unsigned)p << 16; return __builtin_bit_cast(float, u);
}
__device__ __forceinline__ float pkhi(int p) {               // high bf16 of packed pair
    unsigned u = (unsigned)p & 0xFFFF0000u; return __builtin_bit_cast(float, u);
}

// Batched reciprocal: one v_rcp_f32 for four positive values (a_i = 1+e, e <= ~2^8:
// product <= ~3.4e8, no overflow; error ~few ulp, far below bf16 rounding).
__device__ __forceinline__ f32x4 rcp4(const f32x4 a) {
    float m01 = a[0] * a[1], m23 = a[2] * a[3];
    float r   = __builtin_amdgcn_rcpf(m01 * m23);
    float r01 = r * m23, r23 = r * m01;
    f32x4 s; s[0] = a[1] * r01; s[1] = a[0] * r01; s[2] = a[3] * r23; s[3] = a[2] * r23;
    return s;
}

__global__ __launch_bounds__(256, 8) void tinymlp_mfma_kernel(
    const float* __restrict__ x1, const float* __restrict__ x2,
    const float* __restrict__ y1, const float* __restrict__ y2,
    const float* __restrict__ W1, const float* __restrict__ b1,
    const float* __restrict__ W2, const float* __restrict__ b2,
    const float* __restrict__ W3,
    float4* __restrict__ out, int ntiles)
{
    // 4 waves x 2048 shorts: per wave R0 @0 (h1, later dz1), R1 @1024 (dz2)
    __shared__ unsigned short lds0[8192];

    const int tid  = threadIdx.x;
    const int w    = tid >> 6;
    const int lane = tid & 63;
    const int n    = lane & 31;   // batch column (and weight row for A-frags)
    const int q5   = lane >> 5;   // k-half / h-half selector

    union U4 { int i[4]; bf16x8 v; };
    U4 A_z1, A_z2a, A_z2b, A_dh1a, A_dh1b, A_dya, A_dyb;

    #pragma unroll
    for (int t = 0; t < 4; ++t) {
        const int j0 = 8 * q5 + 2 * t;
        const int j1 = j0 + 1;
        // z2: A[h2=n][k=h1], forward scale folded
        A_z2a.i[t] = cvt_pk_bf16(NLOG2E * W2[j0 * H + n],        NLOG2E * W2[j1 * H + n]);
        A_z2b.i[t] = cvt_pk_bf16(NLOG2E * W2[(16 + j0) * H + n], NLOG2E * W2[(16 + j1) * H + n]);
        // dh1: A[h1=n][k=h2], W3 pre-folded
        A_dh1a.i[t] = cvt_pk_bf16(W2[n * H + j0] * W3[j0],           W2[n * H + j1] * W3[j1]);
        A_dh1b.i[t] = cvt_pk_bf16(W2[n * H + 16 + j0] * W3[16 + j0], W2[n * H + 16 + j1] * W3[16 + j1]);
        // dy: A[c=n][k=h1], rows >= 2 zero
        A_dya.i[t] = (n < 2) ? cvt_pk_bf16(W1[n * H + j0],      W1[n * H + j1])      : 0;
        A_dyb.i[t] = (n < 2) ? cvt_pk_bf16(W1[n * H + 16 + j0], W1[n * H + 16 + j1]) : 0;
    }

    // z1 A-frag: k-slots (q5==0 half): {whi0,whi1, wlo0,wlo1, whi0,whi1, b1hi,b1lo}
    // pairing with B = {y1hi,y2hi, y1hi,y2hi, y1lo,y2lo, 1,1}; q5==1 half all zero.
    A_z1.i[0] = A_z1.i[1] = A_z1.i[2] = A_z1.i[3] = 0;
    if (q5 == 0) {
        const float wa = NLOG2E * W1[n];
        const float wb = NLOG2E * W1[H + n];
        const float bv = NLOG2E * b1[n];
        const int hi  = cvt_pk_bf16(wa, wb);
        const int lo  = cvt_pk_bf16(wa - pklo(hi), wb - pkhi(hi));
        const int bh  = cvt_pk_bf16(bv, 0.f);
        const int bhl = cvt_pk_bf16(bv, bv - pklo(bh));
        A_z1.i[0] = hi; A_z1.i[1] = lo; A_z1.i[2] = hi; A_z1.i[3] = bhl;
    }

    // acc init for z2: -log2e*b2 at rows h2 = (r&3)+8*(r>>2)+4*q5
    f32x16 b2C;
    #pragma unroll
    for (int t = 0; t < 4; ++t) {
        const float4 bt = *(const float4*)&b2[8 * t + 4 * q5];
        b2C[4 * t + 0] = NLOG2E * bt.x; b2C[4 * t + 1] = NLOG2E * bt.y;
        b2C[4 * t + 2] = NLOG2E * bt.z; b2C[4 * t + 3] = NLOG2E * bt.w;
    }

    f32x16 zf16;
    #pragma unroll
    for (int r = 0; r < 16; ++r) zf16[r] = 0.f;

    unsigned short*       wb = &lds0[w * 2048 + n * 8 + q5 * 4];
    const unsigned short* rb = &lds0[w * 2048 + q5 * 256 + n * 8];

    const int gwave  = (blockIdx.x * blockDim.x + tid) >> 6;
    const int nwaves = (gridDim.x * blockDim.x) >> 6;
    unsigned idx = (unsigned)gwave * 32 + (unsigned)n;   // lanes 0-31 load/store
    const unsigned step = (unsigned)nwaves * 32;

    for (int tt = gwave; tt < ntiles; tt += nwaves) {
        float y1v = 0.f, y2v = 0.f;
        if (lane < 32) { y1v = y1[idx]; y2v = y2[idx]; }

        // ---- B-frag for z1: y hi/lo split; upper-half A is zero so uY there is don't-care
        U4 uY;
        const int pkHI = cvt_pk_bf16(y1v, y2v);
        const int pkLO = cvt_pk_bf16(y1v - pklo(pkHI), y2v - pkhi(pkHI));
        uY.i[0] = pkHI; uY.i[1] = pkHI; uY.i[2] = pkLO;
        uY.i[3] = 0x3F803F80;   // (1.0,1.0) bias slots

        // ---- z1^T (scaled): one 32x32x16 MFMA ----
        const f32x16 acc = MFMA32(A_z1.v, uY.v, zf16, 0, 0, 0);

        // ---- sigmoid layer 1: 16 exp2 + 4 rcp; scatter s to R0; h1d kept in regs ----
        f32x2 h1d[8];
        #pragma unroll
        for (int t = 0; t < 4; ++t) {
            f32x4 e;
            #pragma unroll
            for (int r = 0; r < 4; ++r) e[r] = __builtin_amdgcn_exp2f(acc[4 * t + r]);
            e += 1.0f;
            const f32x4 s = rcp4(e);
            int2 v;
            v.x = cvt_pk_bf16(s[0], s[1]);
            v.y = cvt_pk_bf16(s[2], s[3]);
            *(int2*)(wb + t * 256) = v;
            f32x2 s01; s01[0] = s[0]; s01[1] = s[1];
            f32x2 s23; s23[0] = s[2]; s23[1] = s[3];
            h1d[2 * t]     = __builtin_elementwise_fma(-s01, s01, s01);  // v_pk_fma_f32
            h1d[2 * t + 1] = __builtin_elementwise_fma(-s23, s23, s23);
        }
        __builtin_amdgcn_wave_barrier();

        // ---- z2^T (scaled, b2 in acc init): K=32 via 2 chained MFMAs ----
        const bf16x8 B1 = *(const bf16x8*)rb;
        const bf16x8 B2 = *(const bf16x8*)(rb + 512);
        f32x16 zz = MFMA32(A_z2a.v, B1, b2C, 0, 0, 0);
        zz = MFMA32(A_z2b.v, B2, zz, 0, 0, 0);

        // ---- dz2 = s2*(1-s2) (W3 folded into dh1 A); pack; scatter to R1 ----
        #pragma unroll
        for (int t = 0; t < 4; ++t) {
            f32x4 e;
            #pragma unroll
            for (int r = 0; r < 4; ++r) e[r] = __builtin_amdgcn_exp2f(zz[4 * t + r]);
            e += 1.0f;
            const f32x4 s = rcp4(e);
            f32x2 sv;
            sv[0] = s[0]; sv[1] = s[1];
            sv = __builtin_elementwise_fma(-sv, sv, sv);
            const int q0 = cvt_pk_bf16(sv[0], sv[1]);
            sv[0] = s[2]; sv[1] = s[3];
            sv = __builtin_elementwise_fma(-sv, sv, sv);
            const int q1 = cvt_pk_bf16(sv[0], sv[1]);
            int2 v; v.x = q0; v.y = q1;
            *(int2*)(wb + 1024 + t * 256) = v;
        }
        __builtin_amdgcn_wave_barrier();

        // x loads here: ~2 stages of latency cover before use in the store
        float xv1 = 0.f, xv2 = 0.f;
        if (lane < 32) { xv1 = x1[idx]; xv2 = x2[idx]; }

        // ---- dH1^T = (W2*W3) @ dZ2^T ----
        const bf16x8 D1 = *(const bf16x8*)(rb + 1024);
        const bf16x8 D2 = *(const bf16x8*)(rb + 1536);
        f32x16 dh = MFMA32(A_dh1a.v, D1, zf16, 0, 0, 0);
        dh = MFMA32(A_dh1b.v, D2, dh, 0, 0, 0);

        // ---- dz1 = dH1 * h1d (register-carried; same C-layout); scatter to R0 ----
        #pragma unroll
        for (int t = 0; t < 4; ++t) {
            f32x2 gg;
            gg[0] = dh[4 * t];     gg[1] = dh[4 * t + 1]; gg *= h1d[2 * t];
            const int g0 = cvt_pk_bf16(gg[0], gg[1]);
            gg[0] = dh[4 * t + 2]; gg[1] = dh[4 * t + 3]; gg *= h1d[2 * t + 1];
            const int g1 = cvt_pk_bf16(gg[0], gg[1]);
            int2 v; v.x = g0; v.y = g1;
            *(int2*)(wb + t * 256) = v;
        }
        __builtin_amdgcn_wave_barrier();

        // ---- dY^T = W1 @ dZ1^T: lanes 0-31 hold g1=reg0, g2=reg1 ----
        const bf16x8 E1 = *(const bf16x8*)rb;
        const bf16x8 E2 = *(const bf16x8*)(rb + 512);
        f32x16 ay = MFMA32(A_dya.v, E1, zf16, 0, 0, 0);
        ay = MFMA32(A_dyb.v, E2, ay, 0, 0, 0);

        if (lane < 32) {
            float4 o;
            o.x = xv1 + ay[0];
            o.y = xv2 + ay[1];
            o.z = y1v;
            o.w = y2v;
            out[idx] = o;
        }
        __builtin_amdgcn_wave_barrier();   // next iter's R0 writes stay behind E-reads

        idx += step;
    }
}

extern "C" void kernel_launch(void* const* d_in, const int* in_sizes, int n_in,
                              void* d_out, int out_size, void* d_ws, size_t ws_size,
                              hipStream_t stream) {
    const float* x1 = (const float*)d_in[0];
    const float* x2 = (const float*)d_in[1];
    const float* y1 = (const float*)d_in[2];
    const float* y2 = (const float*)d_in[3];
    const float* W1 = (const float*)d_in[4];
    const float* b1 = (const float*)d_in[5];
    const float* W2 = (const float*)d_in[6];
    const float* b2 = (const float*)d_in[7];
    const float* W3 = (const float*)d_in[8];
    // d_in[9] = b3: drops out of the input-gradient — unused.

    const int n = in_sizes[0];
    const int ntiles = n / 32;       // B = 4194304 -> 131072 tiles of 32
    const int block = 256;           // 4 waves
    const int grid = 2048;           // 8 blocks/CU resident (16 KB LDS x 8 = 128 KB, <=64 VGPR)
    tinymlp_mfma_kernel<<<grid, block, 0, stream>>>(
        x1, x2, y1, y2, W1, b1, W2, b2, W3, (float4*)d_out, ntiles);
}

// Round 8
// 329.470 us; speedup vs baseline: 1.3572x; 1.3572x over previous
//
#include <hip/hip_runtime.h>

// TinyMLP (2 -> 32 -> 32 -> 1, sigmoid) analytic input-gradient, fused, MFMA-based.
// R8: EXACT R5 structure (VGPR=40 measured, no spill) with occupancy restored to
// 8 waves/SIMD (launch_bounds(256,8), grid 2048). The R6/R7 h1d register carry is
// REVERTED: +16 VGPR under the 64-reg cap caused a scratch-spill catastrophe
// (VGPR_Count 40->32 while FETCH 37->775MB, WRITE 72->366MB — spill signature,
// same as R4). h1d is recomputed from packed bf16 s in the dz1 loop (R5 code).
// TRANSPOSED dataflow: batch on the 32-wide column dim (lane&31) throughout;
// weights are wave-invariant A-operands; q5 = lane>>5 selects the h/k half.
//   MFMA z1  (x1): -log2e*Z1^T = A_z1 @ Y^T    (y hi/lo bf16 split, b1 in K-slots 6,7)
//   MFMA z2  (x2): -log2e*Z2^T = W2s @ H1^T    (K=32 chained; acc init = -log2e*b2)
//   MFMA dh1 (x2): dH1^T = (W2*W3) @ dZ2^T     (W3 folded into weights at init)
//   MFMA dy  (x2): dY^T  = W1 @ dZ1^T          (g1,g2 = regs 0,1 of lanes 0-31)
// Evidence: R5 at 6 waves/SIMD shows VALUBusy 52% with each wave ~91% stalled
// (1082cy issue demand vs 12.5Kcy wall) -> TLP-starved. This round isolates the
// occupancy variable with zero structural change.
//
// Layouts (32x32x16 bf16; C verified m74/m101, A/B verified-by-run R5):
//   A-frag: lane holds A[row=lane&31][k=(lane>>5)*8+j]
//   B-frag: lane holds B[k=(lane>>5)*8+j][n=lane&31]
//   C/D:    lane holds D[row=(reg&3)+8*(reg>>2)+4*(lane>>5)][col=lane&31]
//
// LDS pivot (per wave, two 1024-short regions R0/R1): value (batch b, k) at short
// index (k>>3)*256 + b*8 + (k&7). Writer lane (q5,b): reg pair (4t+e) has k =
// 8t+4q5+e -> one int2 at t*256 + b*8 + 4q5 per t (4x ds_write_b64). Reader lane
// (q5,n): 8 shorts at blk*256 + n*8 (ds_read_b128).

#define H 32
#define NLOG2E (-1.4426950408889634f)

typedef __attribute__((ext_vector_type(8))) short bf16x8;
typedef __attribute__((ext_vector_type(16))) float f32x16;
typedef __attribute__((ext_vector_type(4))) float f32x4;
typedef __attribute__((ext_vector_type(2))) float f32x2;
typedef __attribute__((ext_vector_type(2))) __bf16 bfx2;

#define MFMA32 __builtin_amdgcn_mfma_f32_32x32x16_bf16

__device__ __forceinline__ int cvt_pk_bf16(float a, float b) {
    f32x2 f; f[0] = a; f[1] = b;
    bfx2 r = __builtin_convertvector(f, bfx2);   // v_cvt_pk_bf16_f32 (RNE)
    return __builtin_bit_cast(int, r);
}
__device__ __forceinline__ float pklo(int p) {               // low bf16 of packed pair
    unsigned u = (unsigned)p << 16; return __builtin_bit_cast(float, u);
}
__device__ __forceinline__ float pkhi(int p) {               // high bf16 of packed pair
    unsigned u = (unsigned)p & 0xFFFF0000u; return __builtin_bit_cast(float, u);
}

// Batched reciprocal: one v_rcp_f32 for four positive values (a_i = 1+e, e <= ~2^8:
// product <= ~3.4e8, no overflow; error ~few ulp, far below bf16 rounding).
__device__ __forceinline__ f32x4 rcp4(const f32x4 a) {
    float m01 = a[0] * a[1], m23 = a[2] * a[3];
    float r   = __builtin_amdgcn_rcpf(m01 * m23);
    float r01 = r * m23, r23 = r * m01;
    f32x4 s; s[0] = a[1] * r01; s[1] = a[0] * r01; s[2] = a[3] * r23; s[3] = a[2] * r23;
    return s;
}

__global__ __launch_bounds__(256, 8) void tinymlp_mfma_kernel(
    const float* __restrict__ x1, const float* __restrict__ x2,
    const float* __restrict__ y1, const float* __restrict__ y2,
    const float* __restrict__ W1, const float* __restrict__ b1,
    const float* __restrict__ W2, const float* __restrict__ b2,
    const float* __restrict__ W3,
    float4* __restrict__ out, int ntiles)
{
    // 4 waves x 2048 shorts: per wave R0 @0 (h1, later dz1), R1 @1024 (dz2)
    __shared__ unsigned short lds0[8192];

    const int tid  = threadIdx.x;
    const int w    = tid >> 6;
    const int lane = tid & 63;
    const int n    = lane & 31;   // batch column (and weight row for A-frags)
    const int q5   = lane >> 5;   // k-half / h-half selector

    union U4 { int i[4]; bf16x8 v; };
    U4 A_z1, A_z2a, A_z2b, A_dh1a, A_dh1b, A_dya, A_dyb;

    #pragma unroll
    for (int t = 0; t < 4; ++t) {
        const int j0 = 8 * q5 + 2 * t;
        const int j1 = j0 + 1;
        // z2: A[h2=n][k=h1], forward scale folded
        A_z2a.i[t] = cvt_pk_bf16(NLOG2E * W2[j0 * H + n],        NLOG2E * W2[j1 * H + n]);
        A_z2b.i[t] = cvt_pk_bf16(NLOG2E * W2[(16 + j0) * H + n], NLOG2E * W2[(16 + j1) * H + n]);
        // dh1: A[h1=n][k=h2], W3 pre-folded
        A_dh1a.i[t] = cvt_pk_bf16(W2[n * H + j0] * W3[j0],           W2[n * H + j1] * W3[j1]);
        A_dh1b.i[t] = cvt_pk_bf16(W2[n * H + 16 + j0] * W3[16 + j0], W2[n * H + 16 + j1] * W3[16 + j1]);
        // dy: A[c=n][k=h1], rows >= 2 zero
        A_dya.i[t] = (n < 2) ? cvt_pk_bf16(W1[n * H + j0],      W1[n * H + j1])      : 0;
        A_dyb.i[t] = (n < 2) ? cvt_pk_bf16(W1[n * H + 16 + j0], W1[n * H + 16 + j1]) : 0;
    }

    // z1 A-frag: k-slots (q5==0 half): {whi0,whi1, wlo0,wlo1, whi0,whi1, b1hi,b1lo}
    // pairing with B = {y1hi,y2hi, y1hi,y2hi, y1lo,y2lo, 1,1}; q5==1 half all zero.
    A_z1.i[0] = A_z1.i[1] = A_z1.i[2] = A_z1.i[3] = 0;
    if (q5 == 0) {
        const float wa = NLOG2E * W1[n];
        const float wb = NLOG2E * W1[H + n];
        const float bv = NLOG2E * b1[n];
        const int hi  = cvt_pk_bf16(wa, wb);
        const int lo  = cvt_pk_bf16(wa - pklo(hi), wb - pkhi(hi));
        const int bh  = cvt_pk_bf16(bv, 0.f);
        const int bhl = cvt_pk_bf16(bv, bv - pklo(bh));
        A_z1.i[0] = hi; A_z1.i[1] = lo; A_z1.i[2] = hi; A_z1.i[3] = bhl;
    }

    // acc init for z2: -log2e*b2 at rows h2 = (r&3)+8*(r>>2)+4*q5
    f32x16 b2C;
    #pragma unroll
    for (int t = 0; t < 4; ++t) {
        const float4 bt = *(const float4*)&b2[8 * t + 4 * q5];
        b2C[4 * t + 0] = NLOG2E * bt.x; b2C[4 * t + 1] = NLOG2E * bt.y;
        b2C[4 * t + 2] = NLOG2E * bt.z; b2C[4 * t + 3] = NLOG2E * bt.w;
    }

    f32x16 zf16;
    #pragma unroll
    for (int r = 0; r < 16; ++r) zf16[r] = 0.f;

    unsigned short*       wb = &lds0[w * 2048 + n * 8 + q5 * 4];
    const unsigned short* rb = &lds0[w * 2048 + q5 * 256 + n * 8];

    const int gwave  = (blockIdx.x * blockDim.x + tid) >> 6;
    const int nwaves = (gridDim.x * blockDim.x) >> 6;
    unsigned idx = (unsigned)gwave * 32 + (unsigned)n;   // lanes 0-31 load/store
    const unsigned step = (unsigned)nwaves * 32;

    for (int tt = gwave; tt < ntiles; tt += nwaves) {
        float y1v = 0.f, y2v = 0.f;
        if (lane < 32) { y1v = y1[idx]; y2v = y2[idx]; }

        // ---- B-frag for z1: y hi/lo split; upper-half A is zero so uY there is don't-care
        U4 uY;
        const int pkHI = cvt_pk_bf16(y1v, y2v);
        const int pkLO = cvt_pk_bf16(y1v - pklo(pkHI), y2v - pkhi(pkHI));
        uY.i[0] = pkHI; uY.i[1] = pkHI; uY.i[2] = pkLO;
        uY.i[3] = 0x3F803F80;   // (1.0,1.0) bias slots

        // ---- z1^T (scaled): one 32x32x16 MFMA ----
        const f32x16 acc = MFMA32(A_z1.v, uY.v, zf16, 0, 0, 0);

        // ---- sigmoid layer 1: 16 exp2 + 4 rcp; pack s -> P; scatter to R0 ----
        int P[8];
        #pragma unroll
        for (int t = 0; t < 4; ++t) {
            f32x4 e;
            #pragma unroll
            for (int r = 0; r < 4; ++r) e[r] = __builtin_amdgcn_exp2f(acc[4 * t + r]);
            e += 1.0f;
            const f32x4 s = rcp4(e);
            P[2 * t]     = cvt_pk_bf16(s[0], s[1]);
            P[2 * t + 1] = cvt_pk_bf16(s[2], s[3]);
            int2 v; v.x = P[2 * t]; v.y = P[2 * t + 1];
            *(int2*)(wb + t * 256) = v;
        }
        __builtin_amdgcn_wave_barrier();

        // ---- z2^T (scaled, b2 in acc init): K=32 via 2 chained MFMAs ----
        const bf16x8 B1 = *(const bf16x8*)rb;
        const bf16x8 B2 = *(const bf16x8*)(rb + 512);
        f32x16 zz = MFMA32(A_z2a.v, B1, b2C, 0, 0, 0);
        zz = MFMA32(A_z2b.v, B2, zz, 0, 0, 0);

        // ---- dz2 = s2*(1-s2) (W3 folded into dh1 A); pack; scatter to R1 ----
        #pragma unroll
        for (int t = 0; t < 4; ++t) {
            f32x4 e;
            #pragma unroll
            for (int r = 0; r < 4; ++r) e[r] = __builtin_amdgcn_exp2f(zz[4 * t + r]);
            e += 1.0f;
            const f32x4 s = rcp4(e);
            f32x2 sv;
            sv[0] = s[0]; sv[1] = s[1];
            sv = __builtin_elementwise_fma(-sv, sv, sv);
            const int q0 = cvt_pk_bf16(sv[0], sv[1]);
            sv[0] = s[2]; sv[1] = s[3];
            sv = __builtin_elementwise_fma(-sv, sv, sv);
            const int q1 = cvt_pk_bf16(sv[0], sv[1]);
            int2 v; v.x = q0; v.y = q1;
            *(int2*)(wb + 1024 + t * 256) = v;
        }
        __builtin_amdgcn_wave_barrier();

        // x loads here: ~2 stages of latency cover before use in the store
        float xv1 = 0.f, xv2 = 0.f;
        if (lane < 32) { xv1 = x1[idx]; xv2 = x2[idx]; }

        // ---- dH1^T = (W2*W3) @ dZ2^T ----
        const bf16x8 D1 = *(const bf16x8*)(rb + 1024);
        const bf16x8 D2 = *(const bf16x8*)(rb + 1536);
        f32x16 dh = MFMA32(A_dh1a.v, D1, zf16, 0, 0, 0);
        dh = MFMA32(A_dh1b.v, D2, dh, 0, 0, 0);

        // ---- dz1 = dH1 * h1d (recomputed from packed bf16 s; same C-layout); -> R0 ----
        #pragma unroll
        for (int t = 0; t < 4; ++t) {
            f32x2 sv, gg;
            sv[0] = pklo(P[2 * t]); sv[1] = pkhi(P[2 * t]);
            sv = __builtin_elementwise_fma(-sv, sv, sv);
            gg[0] = dh[4 * t]; gg[1] = dh[4 * t + 1]; gg *= sv;
            const int g0 = cvt_pk_bf16(gg[0], gg[1]);
            sv[0] = pklo(P[2 * t + 1]); sv[1] = pkhi(P[2 * t + 1]);
            sv = __builtin_elementwise_fma(-sv, sv, sv);
            gg[0] = dh[4 * t + 2]; gg[1] = dh[4 * t + 3]; gg *= sv;
            const int g1 = cvt_pk_bf16(gg[0], gg[1]);
            int2 v; v.x = g0; v.y = g1;
            *(int2*)(wb + t * 256) = v;
        }
        __builtin_amdgcn_wave_barrier();

        // ---- dY^T = W1 @ dZ1^T: lanes 0-31 hold g1=reg0, g2=reg1 ----
        const bf16x8 E1 = *(const bf16x8*)rb;
        const bf16x8 E2 = *(const bf16x8*)(rb + 512);
        f32x16 ay = MFMA32(A_dya.v, E1, zf16, 0, 0, 0);
        ay = MFMA32(A_dyb.v, E2, ay, 0, 0, 0);

        if (lane < 32) {
            float4 o;
            o.x = xv1 + ay[0];
            o.y = xv2 + ay[1];
            o.z = y1v;
            o.w = y2v;
            out[idx] = o;
        }
        __builtin_amdgcn_wave_barrier();   // next iter's R0 writes stay behind E-reads

        idx += step;
    }
}

extern "C" void kernel_launch(void* const* d_in, const int* in_sizes, int n_in,
                              void* d_out, int out_size, void* d_ws, size_t ws_size,
                              hipStream_t stream) {
    const float* x1 = (const float*)d_in[0];
    const float* x2 = (const float*)d_in[1];
    const float* y1 = (const float*)d_in[2];
    const float* y2 = (const float*)d_in[3];
    const float* W1 = (const float*)d_in[4];
    const float* b1 = (const float*)d_in[5];
    const float* W2 = (const float*)d_in[6];
    const float* b2 = (const float*)d_in[7];
    const float* W3 = (const float*)d_in[8];
    // d_in[9] = b3: drops out of the input-gradient — unused.

    const int n = in_sizes[0];
    const int ntiles = n / 32;       // B = 4194304 -> 131072 tiles of 32
    const int block = 256;           // 4 waves
    const int grid = 2048;           // 8 blocks/CU (16 KB LDS x 8 = 128 KB; VGPR 40 <= 64)
    tinymlp_mfma_kernel<<<grid, block, 0, stream>>>(
        x1, x2, y1, y2, W1, b1, W2, b2, W3, (float4*)d_out, ntiles);
}

// Round 9
// 205.450 us; speedup vs baseline: 2.1765x; 1.6036x over previous
//
#include <hip/hip_runtime.h>

// TinyMLP (2 -> 32 -> 32 -> 1, sigmoid) analytic input-gradient, fused, MFMA-based.
// R9: ALL THREE LDS PIVOTS REPLACED BY v_permlane32_swap_b32 — zero LDS, zero
// barriers, pure-register loop body.
// Evidence: R1/R5 both show wall/tile/wave = ~12x issue demand (serial per-wave
// chain; avg producer->consumer latency ~12cy/slot); N resident waves fill ~N/12
// of issue slots (52% @6, 55% @8). 8 waves is unreachable (R7/R8: true reg need
// 65-84 incl. MFMA accums; cap 64 -> scratch-spill catastrophe). So: cut the chain.
// The LDS round trips (~130cy each + scheduling fences) were the biggest links.
//
// Pivot-by-swap derivation (32x32x16; C-layout row=(reg&3)+8*(reg>>2)+4*q5, col=n):
// lane n and lane n+32 jointly hold all 32 rows of batch col n. Packed int P[2t+i]
// holds rows (8t+4q5+2i, +1). v_permlane32_swap_b32 d,s does d.hi<->s.lo, i.e.
// d' = [d.lo|s.lo], s' = [d.hi|s.hi]. For B-frag int i (k = 8q5+2i) of the next
// MFMA:  swap(P[0],P[2]) -> d' is exactly int0 for BOTH halves (q5=0: own rows 0,1;
// q5=1: partner rows 8,9) and s' is exactly int2 (q5=0: partner 4,5; q5=1: own
// 12,13). So per pivot: 4 swaps, no selects, no LDS, no barrier.
//   MFMA z1  (x1): -log2e*Z1^T = A_z1 @ Y^T    (y hi/lo bf16 split, b1 in K-slots 6,7)
//   MFMA z2  (x2): -log2e*Z2^T = W2s @ H1^T    (K=32; acc init = -log2e*b2)
//   MFMA dh1 (x2): dH1^T = (W2*W3) @ dZ2^T     (W3 folded into weights at init)
//   MFMA dy  (x2): dY^T  = W1 @ dZ1^T          (g1,g2 = regs 0,1 of lanes 0-31)
// Occupancy held at proven-safe 6 waves/SIMD (bounds(256,6), grid 1536) — the R7/R8
// spill tell (VGPR_Count drop + FETCH/WRITE balloon) is the check for this round.
//
// Layouts (32x32x16 bf16; verified-by-run R5):
//   A-frag: lane holds A[row=lane&31][k=(lane>>5)*8+j]
//   B-frag: lane holds B[k=(lane>>5)*8+j][n=lane&31]
//   C/D:    lane holds D[row=(reg&3)+8*(reg>>2)+4*(lane>>5)][col=lane&31]

#define H 32
#define NLOG2E (-1.4426950408889634f)

typedef __attribute__((ext_vector_type(8))) short bf16x8;
typedef __attribute__((ext_vector_type(16))) float f32x16;
typedef __attribute__((ext_vector_type(4))) float f32x4;
typedef __attribute__((ext_vector_type(2))) float f32x2;
typedef __attribute__((ext_vector_type(2))) __bf16 bfx2;

#define MFMA32 __builtin_amdgcn_mfma_f32_32x32x16_bf16

__device__ __forceinline__ int cvt_pk_bf16(float a, float b) {
    f32x2 f; f[0] = a; f[1] = b;
    bfx2 r = __builtin_convertvector(f, bfx2);   // v_cvt_pk_bf16_f32 (RNE)
    return __builtin_bit_cast(int, r);
}
__device__ __forceinline__ float pklo(int p) {               // low bf16 of packed pair
    unsigned u = (unsigned)p << 16; return __builtin_bit_cast(float, u);
}
__device__ __forceinline__ float pkhi(int p) {               // high bf16 of packed pair
    unsigned u = (unsigned)p & 0xFFFF0000u; return __builtin_bit_cast(float, u);
}

// d.hi <-> s.lo (gfx950): after the asm, d = [d.lo|s.lo], s = [d.hi|s.hi].
__device__ __forceinline__ void plane32_swap(int &d, int &s) {
    asm volatile("v_permlane32_swap_b32 %0, %1" : "+v"(d), "+v"(s));
}

// Batched reciprocal: one v_rcp_f32 for four positive values (a_i = 1+e, e <= ~2^8:
// product <= ~3.4e8, no overflow; error ~few ulp, far below bf16 rounding).
__device__ __forceinline__ f32x4 rcp4(const f32x4 a) {
    float m01 = a[0] * a[1], m23 = a[2] * a[3];
    float r   = __builtin_amdgcn_rcpf(m01 * m23);
    float r01 = r * m23, r23 = r * m01;
    f32x4 s; s[0] = a[1] * r01; s[1] = a[0] * r01; s[2] = a[3] * r23; s[3] = a[2] * r23;
    return s;
}

__global__ __launch_bounds__(256, 6) void tinymlp_mfma_kernel(
    const float* __restrict__ x1, const float* __restrict__ x2,
    const float* __restrict__ y1, const float* __restrict__ y2,
    const float* __restrict__ W1, const float* __restrict__ b1,
    const float* __restrict__ W2, const float* __restrict__ b2,
    const float* __restrict__ W3,
    float4* __restrict__ out, int ntiles)
{
    const int tid  = threadIdx.x;
    const int lane = tid & 63;
    const int n    = lane & 31;   // batch column (and weight row for A-frags)
    const int q5   = lane >> 5;   // k-half / h-half selector

    union U4 { int i[4]; bf16x8 v; };
    U4 A_z1, A_z2a, A_z2b, A_dh1a, A_dh1b, A_dya, A_dyb;

    #pragma unroll
    for (int t = 0; t < 4; ++t) {
        const int j0 = 8 * q5 + 2 * t;
        const int j1 = j0 + 1;
        // z2: A[h2=n][k=h1], forward scale folded
        A_z2a.i[t] = cvt_pk_bf16(NLOG2E * W2[j0 * H + n],        NLOG2E * W2[j1 * H + n]);
        A_z2b.i[t] = cvt_pk_bf16(NLOG2E * W2[(16 + j0) * H + n], NLOG2E * W2[(16 + j1) * H + n]);
        // dh1: A[h1=n][k=h2], W3 pre-folded
        A_dh1a.i[t] = cvt_pk_bf16(W2[n * H + j0] * W3[j0],           W2[n * H + j1] * W3[j1]);
        A_dh1b.i[t] = cvt_pk_bf16(W2[n * H + 16 + j0] * W3[16 + j0], W2[n * H + 16 + j1] * W3[16 + j1]);
        // dy: A[c=n][k=h1], rows >= 2 zero
        A_dya.i[t] = (n < 2) ? cvt_pk_bf16(W1[n * H + j0],      W1[n * H + j1])      : 0;
        A_dyb.i[t] = (n < 2) ? cvt_pk_bf16(W1[n * H + 16 + j0], W1[n * H + 16 + j1]) : 0;
    }

    // z1 A-frag: k-slots (q5==0 half): {whi0,whi1, wlo0,wlo1, whi0,whi1, b1hi,b1lo}
    // pairing with B = {y1hi,y2hi, y1hi,y2hi, y1lo,y2lo, 1,1}; q5==1 half all zero.
    A_z1.i[0] = A_z1.i[1] = A_z1.i[2] = A_z1.i[3] = 0;
    if (q5 == 0) {
        const float wa = NLOG2E * W1[n];
        const float wb = NLOG2E * W1[H + n];
        const float bv = NLOG2E * b1[n];
        const int hi  = cvt_pk_bf16(wa, wb);
        const int lo  = cvt_pk_bf16(wa - pklo(hi), wb - pkhi(hi));
        const int bh  = cvt_pk_bf16(bv, 0.f);
        const int bhl = cvt_pk_bf16(bv, bv - pklo(bh));
        A_z1.i[0] = hi; A_z1.i[1] = lo; A_z1.i[2] = hi; A_z1.i[3] = bhl;
    }

    // acc init for z2: -log2e*b2 at rows h2 = (r&3)+8*(r>>2)+4*q5
    f32x16 b2C;
    #pragma unroll
    for (int t = 0; t < 4; ++t) {
        const float4 bt = *(const float4*)&b2[8 * t + 4 * q5];
        b2C[4 * t + 0] = NLOG2E * bt.x; b2C[4 * t + 1] = NLOG2E * bt.y;
        b2C[4 * t + 2] = NLOG2E * bt.z; b2C[4 * t + 3] = NLOG2E * bt.w;
    }

    f32x16 zf16;
    #pragma unroll
    for (int r = 0; r < 16; ++r) zf16[r] = 0.f;

    const int gwave  = (blockIdx.x * blockDim.x + tid) >> 6;
    const int nwaves = (gridDim.x * blockDim.x) >> 6;
    unsigned idx = (unsigned)gwave * 32 + (unsigned)n;   // lanes 0-31 load/store
    const unsigned step = (unsigned)nwaves * 32;

    for (int tt = gwave; tt < ntiles; tt += nwaves) {
        float y1v = 0.f, y2v = 0.f, xv1 = 0.f, xv2 = 0.f;
        if (lane < 32) {
            y1v = y1[idx]; y2v = y2[idx];
            xv1 = x1[idx]; xv2 = x2[idx];
        }

        // ---- B-frag for z1: y hi/lo split; upper-half A is zero so uY there is don't-care
        U4 uY;
        const int pkHI = cvt_pk_bf16(y1v, y2v);
        const int pkLO = cvt_pk_bf16(y1v - pklo(pkHI), y2v - pkhi(pkHI));
        uY.i[0] = pkHI; uY.i[1] = pkHI; uY.i[2] = pkLO;
        uY.i[3] = 0x3F803F80;   // (1.0,1.0) bias slots

        // ---- z1^T (scaled): one 32x32x16 MFMA ----
        const f32x16 acc = MFMA32(A_z1.v, uY.v, zf16, 0, 0, 0);

        // ---- sigmoid layer 1: 16 exp2 + 4 rcp; pack s -> P (kept for h1d) ----
        int P[8];
        #pragma unroll
        for (int t = 0; t < 4; ++t) {
            f32x4 e;
            #pragma unroll
            for (int r = 0; r < 4; ++r) e[r] = __builtin_amdgcn_exp2f(acc[4 * t + r]);
            e += 1.0f;
            const f32x4 s = rcp4(e);
            P[2 * t]     = cvt_pk_bf16(s[0], s[1]);
            P[2 * t + 1] = cvt_pk_bf16(s[2], s[3]);
        }

        // ---- pivot h1 C->B via permlane32_swap (copies preserve P for h1d) ----
        U4 B1f, B2f;
        {
            int a0 = P[0], a2 = P[2]; plane32_swap(a0, a2);
            int a1 = P[1], a3 = P[3]; plane32_swap(a1, a3);
            B1f.i[0] = a0; B1f.i[1] = a1; B1f.i[2] = a2; B1f.i[3] = a3;
            int b0 = P[4], b2i = P[6]; plane32_swap(b0, b2i);
            int b1i = P[5], b3 = P[7]; plane32_swap(b1i, b3);
            B2f.i[0] = b0; B2f.i[1] = b1i; B2f.i[2] = b2i; B2f.i[3] = b3;
        }

        // ---- z2^T (scaled, b2 in acc init): K=32 via 2 chained MFMAs ----
        f32x16 zz = MFMA32(A_z2a.v, B1f.v, b2C, 0, 0, 0);
        zz = MFMA32(A_z2b.v, B2f.v, zz, 0, 0, 0);

        // ---- dz2 = s2*(1-s2) (W3 folded into dh1 A); pack Q ----
        int Q[8];
        #pragma unroll
        for (int t = 0; t < 4; ++t) {
            f32x4 e;
            #pragma unroll
            for (int r = 0; r < 4; ++r) e[r] = __builtin_amdgcn_exp2f(zz[4 * t + r]);
            e += 1.0f;
            const f32x4 s = rcp4(e);
            f32x2 sv;
            sv[0] = s[0]; sv[1] = s[1];
            sv = __builtin_elementwise_fma(-sv, sv, sv);
            Q[2 * t] = cvt_pk_bf16(sv[0], sv[1]);
            sv[0] = s[2]; sv[1] = s[3];
            sv = __builtin_elementwise_fma(-sv, sv, sv);
            Q[2 * t + 1] = cvt_pk_bf16(sv[0], sv[1]);
        }

        // ---- pivot dz2 C->B via swaps (Q dead after; swap in place) ----
        U4 D1f, D2f;
        plane32_swap(Q[0], Q[2]);
        plane32_swap(Q[1], Q[3]);
        D1f.i[0] = Q[0]; D1f.i[1] = Q[1]; D1f.i[2] = Q[2]; D1f.i[3] = Q[3];
        plane32_swap(Q[4], Q[6]);
        plane32_swap(Q[5], Q[7]);
        D2f.i[0] = Q[4]; D2f.i[1] = Q[5]; D2f.i[2] = Q[6]; D2f.i[3] = Q[7];

        // ---- dH1^T = (W2*W3) @ dZ2^T ----
        f32x16 dh = MFMA32(A_dh1a.v, D1f.v, zf16, 0, 0, 0);
        dh = MFMA32(A_dh1b.v, D2f.v, dh, 0, 0, 0);

        // ---- dz1 = dH1 * h1d (h1d recomputed from packed bf16 s); pack G ----
        int G[8];
        #pragma unroll
        for (int t = 0; t < 4; ++t) {
            f32x2 sv, gg;
            sv[0] = pklo(P[2 * t]); sv[1] = pkhi(P[2 * t]);
            sv = __builtin_elementwise_fma(-sv, sv, sv);
            gg[0] = dh[4 * t]; gg[1] = dh[4 * t + 1]; gg *= sv;
            G[2 * t] = cvt_pk_bf16(gg[0], gg[1]);
            sv[0] = pklo(P[2 * t + 1]); sv[1] = pkhi(P[2 * t + 1]);
            sv = __builtin_elementwise_fma(-sv, sv, sv);
            gg[0] = dh[4 * t + 2]; gg[1] = dh[4 * t + 3]; gg *= sv;
            G[2 * t + 1] = cvt_pk_bf16(gg[0], gg[1]);
        }

        // ---- pivot dz1 C->B via swaps (G dead after) ----
        U4 E1f, E2f;
        plane32_swap(G[0], G[2]);
        plane32_swap(G[1], G[3]);
        E1f.i[0] = G[0]; E1f.i[1] = G[1]; E1f.i[2] = G[2]; E1f.i[3] = G[3];
        plane32_swap(G[4], G[6]);
        plane32_swap(G[5], G[7]);
        E2f.i[0] = G[4]; E2f.i[1] = G[5]; E2f.i[2] = G[6]; E2f.i[3] = G[7];

        // ---- dY^T = W1 @ dZ1^T: lanes 0-31 hold g1=reg0, g2=reg1 ----
        f32x16 ay = MFMA32(A_dya.v, E1f.v, zf16, 0, 0, 0);
        ay = MFMA32(A_dyb.v, E2f.v, ay, 0, 0, 0);

        if (lane < 32) {
            float4 o;
            o.x = xv1 + ay[0];
            o.y = xv2 + ay[1];
            o.z = y1v;
            o.w = y2v;
            out[idx] = o;
        }

        idx += step;
    }
}

extern "C" void kernel_launch(void* const* d_in, const int* in_sizes, int n_in,
                              void* d_out, int out_size, void* d_ws, size_t ws_size,
                              hipStream_t stream) {
    const float* x1 = (const float*)d_in[0];
    const float* x2 = (const float*)d_in[1];
    const float* y1 = (const float*)d_in[2];
    const float* y2 = (const float*)d_in[3];
    const float* W1 = (const float*)d_in[4];
    const float* b1 = (const float*)d_in[5];
    const float* W2 = (const float*)d_in[6];
    const float* b2 = (const float*)d_in[7];
    const float* W3 = (const float*)d_in[8];
    // d_in[9] = b3: drops out of the input-gradient — unused.

    const int n = in_sizes[0];
    const int ntiles = n / 32;       // B = 4194304 -> 131072 tiles of 32
    const int block = 256;           // 4 waves
    const int grid = 1536;           // 6 blocks/CU (proven no-spill cap: 84 regs incl. accums)
    tinymlp_mfma_kernel<<<grid, block, 0, stream>>>(
        x1, x2, y1, y2, W1, b1, W2, b2, W3, (float4*)d_out, ntiles);
}